// Round 11
// baseline (170.429 us; speedup 1.0000x reference)
//
#include <hip/hip_runtime.h>
#include <stdint.h>
#include <stddef.h>

#define M_DIM 2048
#define N_DIM 11008
#define K_DIM 4096
#define BM 64
#define BN 128
#define BKB 128            // K-bytes per tile (int8) -> 128B rows (conflict-free XOR geometry)
#define NT (K_DIM / BKB)   // 32
#define NBM (M_DIM / BM)   // 32
#define NBN (N_DIM / BN)   // 86
#define GRID (NBM * NBN)   // 2752 (divisible by 8 -> XCD swizzle bijective)

typedef __attribute__((ext_vector_type(4))) int i4;
typedef __attribute__((ext_vector_type(4))) float f4;

#define VMCNT0() asm volatile("s_waitcnt vmcnt(0)" ::: "memory")
#define FENCE() asm volatile("" ::: "memory")
#define BARRIER()                 \
  do {                            \
    FENCE();                      \
    __builtin_amdgcn_s_barrier(); \
    FENCE();                      \
  } while (0)

__device__ inline void gload_lds16(const void* g, void* l) {
  __builtin_amdgcn_global_load_lds((const __attribute__((address_space(1))) void*)g,
                                   (__attribute__((address_space(3))) void*)l, 16, 0, 0);
}

// ---------------- conversion kernels ----------------

// x[row][4096] fp32 -> per-row int8 with scale xs[row] = rowmax/127 (symmetric RNE).
__global__ void __launch_bounds__(256) quant_x_kernel(const float* __restrict__ x,
                                                      signed char* __restrict__ xq,
                                                      float* __restrict__ xs) {
  __shared__ float red[256];
  const int row = blockIdx.x;
  const int tid = threadIdx.x;
  const f4* xr = (const f4*)(x + (size_t)row * K_DIM);  // 1024 f4 per row
  f4 v[4];
  float mx = 0.f;
#pragma unroll
  for (int j = 0; j < 4; ++j) {
    v[j] = xr[tid * 4 + j];
#pragma unroll
    for (int e = 0; e < 4; ++e) mx = fmaxf(mx, fabsf(v[j][e]));
  }
  red[tid] = mx;
  __syncthreads();
  for (int off = 128; off; off >>= 1) {
    if (tid < off) red[tid] = fmaxf(red[tid], red[tid + off]);
    __syncthreads();
  }
  const float rowmax = red[0];
  const float r = (rowmax > 0.f) ? 127.f / rowmax : 0.f;
  int p[4];
#pragma unroll
  for (int j = 0; j < 4; ++j) {
    int q[4];
#pragma unroll
    for (int e = 0; e < 4; ++e) {
      int qi = __float2int_rn(v[j][e] * r);
      qi = qi > 127 ? 127 : (qi < -127 ? -127 : qi);
      q[e] = qi;
    }
    p[j] = (q[0] & 255) | ((q[1] & 255) << 8) | ((q[2] & 255) << 16) | (q[3] << 24);
  }
  ((i4*)xq)[(size_t)row * 256 + tid] = i4{p[0], p[1], p[2], p[3]};
  if (tid == 0) xs[row] = (rowmax > 0.f) ? rowmax / 127.f : 1.f;
}

// W_q arrives as int32 per element (range [-127,127]); pack low bytes -> int8.
__global__ void __launch_bounds__(256) cvt_w_kernel(const int* __restrict__ w,
                                                    i4* __restrict__ wq8, int n16) {
  int i = blockIdx.x * 256 + threadIdx.x;
  if (i >= n16) return;
  const i4* src = (const i4*)w + 4 * (size_t)i;
  i4 v0 = src[0], v1 = src[1], v2 = src[2], v3 = src[3];
  i4 o;
  o[0] = (v0[0] & 255) | ((v0[1] & 255) << 8) | ((v0[2] & 255) << 16) | (v0[3] << 24);
  o[1] = (v1[0] & 255) | ((v1[1] & 255) << 8) | ((v1[2] & 255) << 16) | (v1[3] << 24);
  o[2] = (v2[0] & 255) | ((v2[1] & 255) << 8) | ((v2[2] & 255) << 16) | (v2[3] << 24);
  o[3] = (v3[0] & 255) | ((v3[1] & 255) << 8) | ((v3[2] & 255) << 16) | (v3[3] << 24);
  wq8[i] = o;
}

// ------- int8 GEMM, 3-blocks/CU: 64x128 tile, BKB=128, 4 waves, 48KB LDS -------
// 4 waves = 2 N-strips (64 cols) x 2 K-halves (64 of 128 bytes); wave-tile 64x64.
// Per wave per tile: 8 ds_read_b128 (a 4, b 4) + 16 x mfma_i32_16x16x64_i8.
// LDS: 2 bufs x 24KB {A[64][128B]@0, B[128][128B]@8K}; 128B rows + XOR swizzle
// byte^=(row&7)<<4 both sides -> 0 bank conflicts (r3-r10 verified geometry).
// Iter t: vmcnt(0) [counted-equivalent: only S(t)'s 6 loads outstanding, issued t-1,
// ~1 block-iter slack]; barrier; STAGE6(t+1) -> other buf; 8 reads; 16 MFMA.
// TLP: 3 blocks/CU (144KB LDS, ~164 regs/wave incl. 64 acc) = 12 waves, 3 barrier
// domains -> latency filled by co-resident blocks (r7 mechanism, scaled up).
// Epilogue: K-half i32 reduce via LDS (fq-XOR, 2-way=free), dequant xs*scale+bias.

#define STAGE6(base, ko)                                                         \
  do {                                                                           \
    const int _ko = (ko);                                                        \
    gload_lds16(gA + _ko, (base) + wid * 1024);                                  \
    gload_lds16(gA + (size_t)32 * K_DIM + _ko, (base) + 4096 + wid * 1024);      \
    gload_lds16(gB + _ko, (base) + 8192 + wid * 1024);                           \
    gload_lds16(gB + (size_t)32 * K_DIM + _ko, (base) + 12288 + wid * 1024);     \
    gload_lds16(gB + (size_t)64 * K_DIM + _ko, (base) + 16384 + wid * 1024);     \
    gload_lds16(gB + (size_t)96 * K_DIM + _ko, (base) + 20480 + wid * 1024);     \
  } while (0)

__global__ void __launch_bounds__(256, 3) gemm_i8(
    const signed char* __restrict__ Xq,   // [M, K] int8
    const signed char* __restrict__ Wq,   // [N, K] int8
    const float* __restrict__ xs,         // [M] row scales
    const float* __restrict__ scale,      // [N]
    const float* __restrict__ bias,       // [N]
    float* __restrict__ out) {            // [M, N] fp32
  __shared__ __align__(16) char lds[49152];  // 2 x 24KB; epilogue reuses 32KB

  const int tid = threadIdx.x;
  const int lane = tid & 63;
  const int wid = tid >> 6;   // 0..3
  const int s = wid & 1;      // N-strip (64 cols)
  const int h = wid >> 1;     // K-half (64 bytes of 128)
  const int fr = lane & 15;
  const int fq = lane >> 4;

  // T1: XCD-aware swizzle (2752 % 8 == 0 -> bijective). Consecutive wg share bn.
  const int bid = blockIdx.x;
  const int wg = (bid & 7) * (GRID / 8) + (bid >> 3);
  const int bm = wg & 31;
  const int bn = wg >> 5;

  // staging source (inverse-swizzled): row = tid>>3 (+32 chunks), granule = (tid&7)^(row&7)
  const int srow = tid >> 3;
  const int scol = ((tid & 7) ^ (srow & 7)) * 16;  // bytes
  const signed char* gA = Xq + (size_t)(bm * BM + srow) * K_DIM + scol;
  const signed char* gB = Wq + (size_t)(bn * BN + srow) * K_DIM + scol;

  // ds_read: byte col = (h*64 + fq*16) ^ ((row&7)<<4); row&7 == lane&7 for all frags
  const int cb = ((h * 64) + (fq * 16)) ^ ((lane & 7) << 4);

  char* const buf0 = lds;
  char* const buf1 = lds + 24576;

  STAGE6(buf0, 0);

  i4 acc[4][4] = {};

#pragma unroll 1
  for (int t = 0; t < NT; ++t) {
    char* const bc = (t & 1) ? buf1 : buf0;
    char* const bo = (t & 1) ? buf0 : buf1;
    VMCNT0();    // S(t) complete (issued iter t-1; ~1 block-iter slack)
    BARRIER();   // publish bc; prior readers of bo drained pre-barrier
    if (t + 1 < NT) STAGE6(bo, (t + 1) * BKB);

    i4 a[4], b[4];
#pragma unroll
    for (int m = 0; m < 4; ++m)
      a[m] = *(const i4*)(bc + (m * 16 + fr) * 128 + cb);
#pragma unroll
    for (int j = 0; j < 4; ++j)
      b[j] = *(const i4*)(bc + 8192 + (s * 64 + j * 16 + fr) * 128 + cb);
    __builtin_amdgcn_s_setprio(1);
#pragma unroll
    for (int m = 0; m < 4; ++m)
#pragma unroll
      for (int j = 0; j < 4; ++j)
        acc[m][j] = __builtin_amdgcn_mfma_i32_16x16x64_i8(a[m], b[j], acc[m][j], 0, 0, 0);
    __builtin_amdgcn_s_setprio(0);
  }

  // ---- epilogue: reduce K-half pairs via LDS (i32, fq-XOR swizzle -> 2-way, free),
  // then dequant + bias + store. C/D frag: col=j*16+fr, row=m*16+fq*4+jj.
  BARRIER();
  if (h == 1) {
    int* red = (int*)(lds + s * 16384);  // [64][64] i32 per strip
#pragma unroll
    for (int m = 0; m < 4; ++m)
#pragma unroll
      for (int j = 0; j < 4; ++j)
#pragma unroll
        for (int jj = 0; jj < 4; ++jj)
          red[(m * 16 + fq * 4 + jj) * 64 + ((j * 16 + fr) ^ (fq << 4))] = acc[m][j][jj];
  }
  BARRIER();
  if (h == 0) {
    const int* red = (const int*)(lds + s * 16384);
#pragma unroll
    for (int j = 0; j < 4; ++j) {
      const int c = bn * BN + s * 64 + j * 16 + fr;
      const float sc = scale[c];
      const float bi = bias[c];
#pragma unroll
      for (int m = 0; m < 4; ++m) {
        const int r0 = bm * BM + m * 16 + fq * 4;
#pragma unroll
        for (int jj = 0; jj < 4; ++jj) {
          const int sum = acc[m][j][jj] +
                          red[(m * 16 + fq * 4 + jj) * 64 + ((j * 16 + fr) ^ (fq << 4))];
          out[(size_t)(r0 + jj) * N_DIM + c] = (float)sum * xs[r0 + jj] * sc + bi;
        }
      }
    }
  }
}

// ---------------- fallback (only if d_ws too small) ----------------

__global__ void __launch_bounds__(256) naive_kernel(
    const float* __restrict__ x, const int* __restrict__ w,
    const float* __restrict__ scale, const float* __restrict__ bias,
    float* __restrict__ out) {
  size_t idx = (size_t)blockIdx.x * 256 + threadIdx.x;
  if (idx >= (size_t)M_DIM * N_DIM) return;
  int m = (int)(idx / N_DIM);
  int n = (int)(idx % N_DIM);
  const float* xr = x + (size_t)m * K_DIM;
  const int* wr = w + (size_t)n * K_DIM;
  float acc = 0.f;
  for (int k = 0; k < K_DIM; k += 4) {
    f4 xv = *(const f4*)(xr + k);
    i4 wv = *(const i4*)(wr + k);
    acc += xv[0] * (float)wv[0];
    acc += xv[1] * (float)wv[1];
    acc += xv[2] * (float)wv[2];
    acc += xv[3] * (float)wv[3];
  }
  out[idx] = acc * scale[n] + bias[n];
}

// ---------------- launch ----------------

extern "C" void kernel_launch(void* const* d_in, const int* in_sizes, int n_in,
                              void* d_out, int out_size, void* d_ws, size_t ws_size,
                              hipStream_t stream) {
  const float* x = (const float*)d_in[0];
  const int* wq = (const int*)d_in[1];
  const float* scale = (const float*)d_in[2];
  const float* bias = (const float*)d_in[3];
  float* out = (float*)d_out;

  const size_t xq_bytes = (size_t)M_DIM * K_DIM;         // 8.4 MB
  const size_t xs_bytes = (size_t)M_DIM * sizeof(float); // 8 KB
  const size_t wq_bytes = (size_t)N_DIM * K_DIM;         // 45.1 MB

  if (ws_size >= xq_bytes + xs_bytes + wq_bytes) {
    signed char* xq = (signed char*)d_ws;
    float* xs = (float*)((char*)d_ws + xq_bytes);
    signed char* wq8 = (signed char*)((char*)d_ws + xq_bytes + xs_bytes);

    quant_x_kernel<<<M_DIM, 256, 0, stream>>>(x, xq, xs);

    const int n16 = N_DIM * K_DIM / 16;
    cvt_w_kernel<<<(n16 + 255) / 256, 256, 0, stream>>>(wq, (i4*)wq8, n16);

    gemm_i8<<<GRID, 256, 0, stream>>>(xq, wq8, xs, scale, bias, out);
  } else {
    const size_t total = (size_t)M_DIM * N_DIM;
    naive_kernel<<<(unsigned)((total + 255) / 256), 256, 0, stream>>>(x, wq, scale, bias, out);
  }
}